// Round 1
// baseline (702.122 us; speedup 1.0000x reference)
//
#include <hip/hip_runtime.h>
#include <hip/hip_bf16.h>
#include <stdint.h>

#define N_NODES 100000
#define N_EDGES 1600000
#define FEAT 128

typedef uint16_t u16;
typedef uint32_t u32;
typedef __attribute__((ext_vector_type(8))) short bf16x8;
typedef __attribute__((ext_vector_type(4))) float f32x4;

__device__ __forceinline__ u16 bf16_rn(float f){
  u32 u = __float_as_uint(f);
  u += 0x7FFFu + ((u >> 16) & 1u);
  return (u16)(u >> 16);
}
__device__ __forceinline__ float bf16_to_f32(u16 h){
  u32 u = ((u32)h) << 16;
  return __uint_as_float(u);
}

// ---------------- CSR build ----------------

__global__ void count_deg_kernel(const int* __restrict__ dst, int* __restrict__ deg){
  int e = blockIdx.x * 256 + threadIdx.x;
  if (e < N_EDGES) atomicAdd(&deg[dst[e]], 1);
}

__global__ void scan_blocks_kernel(const int* __restrict__ deg, int* __restrict__ offs,
                                   int* __restrict__ bsums){
  __shared__ int s[1024];
  int t = threadIdx.x;
  int i = blockIdx.x * 1024 + t;
  int v = (i < N_NODES) ? deg[i] : 0;
  s[t] = v;
  __syncthreads();
  for (int d = 1; d < 1024; d <<= 1){
    int add = (t >= d) ? s[t - d] : 0;
    __syncthreads();
    s[t] += add;
    __syncthreads();
  }
  if (i < N_NODES) offs[i] = s[t] - v;   // exclusive within block
  if (t == 1023) bsums[blockIdx.x] = s[1023];
}

__global__ void scan_sums_kernel(int* __restrict__ bsums, int nb){
  if (threadIdx.x == 0 && blockIdx.x == 0){
    int run = 0;
    for (int b = 0; b < nb; ++b){
      int t = bsums[b];
      bsums[b] = run;
      run += t;
    }
  }
}

__global__ void finalize_kernel(const int* __restrict__ deg, int* __restrict__ offs,
                                const int* __restrict__ bsums, float* __restrict__ inv_deg){
  int i = blockIdx.x * 256 + threadIdx.x;
  if (i < N_NODES){
    offs[i] += bsums[i >> 10];
    float d = (float)deg[i];
    inv_deg[i] = 1.0f / fmaxf(d, 1.0f);
  }
}

__global__ void fill_csr_kernel(const int* __restrict__ src, const int* __restrict__ dst,
                                const int* __restrict__ offs, int* __restrict__ cursor,
                                int* __restrict__ eidx){
  int e = blockIdx.x * 256 + threadIdx.x;
  if (e < N_EDGES){
    int d = dst[e];
    int p = atomicAdd(&cursor[d], 1);
    eidx[offs[d] + p] = src[e];
  }
}

// ---------------- W pre-shuffle to B-fragment order ----------------
// Wp[((n0*4+k0)*64 + lane)*8 + j] = bf16( W[(k0*32 + (lane>>4)*8 + j)*128 + n0*16 + (lane&15)] )
__global__ void wprep_kernel(const float* __restrict__ W, u16* __restrict__ Wp){
  int idx = blockIdx.x * 256 + threadIdx.x;     // 0..16383
  int j    = idx & 7;
  int lane = (idx >> 3) & 63;
  int t    = idx >> 9;                          // n0*4 + k0
  int k0 = t & 3, n0 = t >> 2;
  int k = k0 * 32 + (lane >> 4) * 8 + j;
  int n = n0 * 16 + (lane & 15);
  Wp[idx] = bf16_rn(W[k * FEAT + n]);
}

// ---------------- aggregation: one wave per dst node ----------------
// T[dst] = h[dst] + inv_deg[dst] * sum_{src in csr[dst]} h[src]   (bf16 out, fp32 accum)
template<bool IN_BF16>
__global__ void agg_kernel(const void* __restrict__ hin,
                           const int* __restrict__ offs,
                           const int* __restrict__ deg,
                           const float* __restrict__ inv_deg,
                           const int* __restrict__ eidx,
                           u16* __restrict__ T){
  int node = (int)((blockIdx.x * (u32)blockDim.x + threadIdx.x) >> 6);
  int lane = threadIdx.x & 63;
  if (node >= N_NODES) return;
  int start = offs[node];
  int cnt   = deg[node];
  float a0 = 0.f, a1 = 0.f;
  for (int base = 0; base < cnt; base += 64){
    int m = cnt - base; if (m > 64) m = 64;
    int myidx = 0;
    if (lane < m) myidx = eidx[start + base + lane];
    for (int e = 0; e < m; ++e){
      int src = __shfl(myidx, e);
      if (IN_BF16){
        u32 p = *(const u32*)((const u16*)hin + (size_t)src * FEAT + 2 * lane);
        a0 += bf16_to_f32((u16)(p & 0xFFFFu));
        a1 += bf16_to_f32((u16)(p >> 16));
      } else {
        float2 v = *(const float2*)((const float*)hin + (size_t)src * FEAT + 2 * lane);
        a0 += v.x; a1 += v.y;
      }
    }
  }
  float w = inv_deg[node];
  float s0, s1;
  if (IN_BF16){
    u32 p = *(const u32*)((const u16*)hin + (size_t)node * FEAT + 2 * lane);
    s0 = bf16_to_f32((u16)(p & 0xFFFFu));
    s1 = bf16_to_f32((u16)(p >> 16));
  } else {
    float2 v = *(const float2*)((const float*)hin + (size_t)node * FEAT + 2 * lane);
    s0 = v.x; s1 = v.y;
  }
  float t0 = s0 + w * a0;
  float t1 = s1 + w * a1;
  u32 o = (u32)bf16_rn(t0) | ((u32)bf16_rn(t1) << 16);
  *(u32*)(T + (size_t)node * FEAT + 2 * lane) = o;
}

// ---------------- GEMM: out = [relu](T @ W + b), per-wave 16x128 strip ----------------
template<bool OUT_F32, bool RELU>
__global__ void gemm_kernel(const u16* __restrict__ T, const u16* __restrict__ Wp,
                            const float* __restrict__ bias, void* __restrict__ out){
  int wave = threadIdx.x >> 6;
  int lane = threadIdx.x & 63;
  int row0 = blockIdx.x * 64 + wave * 16;
  if (row0 >= N_NODES) return;
  int quad = lane >> 4;
  int c    = lane & 15;

  f32x4 acc[8];
  #pragma unroll
  for (int i = 0; i < 8; ++i) acc[i] = (f32x4){0.f, 0.f, 0.f, 0.f};

  // A fragment: lane holds A[m=lane&15][k = quad*8 + j], contiguous 8 bf16 in row
  const u16* arow = T + (size_t)(row0 + c) * FEAT + quad * 8;
  #pragma unroll
  for (int k0 = 0; k0 < 4; ++k0){
    bf16x8 a = *(const bf16x8*)(arow + k0 * 32);
    #pragma unroll
    for (int n0 = 0; n0 < 8; ++n0){
      bf16x8 b = *(const bf16x8*)(Wp + (((n0 << 2) | k0) * 64 + lane) * 8);
      acc[n0] = __builtin_amdgcn_mfma_f32_16x16x32_bf16(a, b, acc[n0], 0, 0, 0);
    }
  }

  // C/D layout: col = lane&15, row = quad*4 + reg
  #pragma unroll
  for (int n0 = 0; n0 < 8; ++n0){
    float bv = bias[n0 * 16 + c];
    #pragma unroll
    for (int r = 0; r < 4; ++r){
      int row = row0 + quad * 4 + r;
      int col = n0 * 16 + c;
      float v = acc[n0][r] + bv;
      if (RELU) v = fmaxf(v, 0.f);
      if (OUT_F32) ((float*)out)[(size_t)row * FEAT + col] = v;
      else         ((u16*)out)[(size_t)row * FEAT + col]   = bf16_rn(v);
    }
  }
}

// ---------------- launch ----------------

static inline size_t align_up(size_t x){ return (x + 255) & ~(size_t)255; }

extern "C" void kernel_launch(void* const* d_in, const int* in_sizes, int n_in,
                              void* d_out, int out_size, void* d_ws, size_t ws_size,
                              hipStream_t stream){
  const float* x  = (const float*)d_in[0];
  const float* W1 = (const float*)d_in[1];
  const float* b1 = (const float*)d_in[2];
  const float* W2 = (const float*)d_in[3];
  const float* b2 = (const float*)d_in[4];
  const float* W3 = (const float*)d_in[5];
  const float* b3 = (const float*)d_in[6];
  const int* esrc = (const int*)d_in[7];
  const int* edst = (const int*)d_in[8];

  char* w = (char*)d_ws;
  int*   deg     = (int*)w;    w += align_up((size_t)N_NODES * 4);
  int*   offs    = (int*)w;    w += align_up((size_t)(N_NODES + 1) * 4);
  int*   cursor  = (int*)w;    w += align_up((size_t)N_NODES * 4);
  int*   bsums   = (int*)w;    w += align_up(1024 * 4);
  float* inv_deg = (float*)w;  w += align_up((size_t)N_NODES * 4);
  int*   eidx    = (int*)w;    w += align_up((size_t)N_EDGES * 4);
  u16*   Wp1     = (u16*)w;    w += align_up((size_t)16384 * 2);
  u16*   Wp2     = (u16*)w;    w += align_up((size_t)16384 * 2);
  u16*   Wp3     = (u16*)w;    w += align_up((size_t)16384 * 2);
  u16*   T       = (u16*)w;    w += align_up((size_t)N_NODES * FEAT * 2);
  u16*   H       = (u16*)d_out;  // intermediate h (bf16) lives in d_out, dead before final write

  hipMemsetAsync(deg,    0, (size_t)N_NODES * 4, stream);
  hipMemsetAsync(cursor, 0, (size_t)N_NODES * 4, stream);

  const int EB = (N_EDGES + 255) / 256;
  const int NB_SCAN = (N_NODES + 1023) / 1024;   // 98

  count_deg_kernel<<<EB, 256, 0, stream>>>(edst, deg);
  scan_blocks_kernel<<<NB_SCAN, 1024, 0, stream>>>(deg, offs, bsums);
  scan_sums_kernel<<<1, 64, 0, stream>>>(bsums, NB_SCAN);
  finalize_kernel<<<(N_NODES + 255) / 256, 256, 0, stream>>>(deg, offs, bsums, inv_deg);
  fill_csr_kernel<<<EB, 256, 0, stream>>>(esrc, edst, offs, cursor, eidx);

  wprep_kernel<<<64, 256, 0, stream>>>(W1, Wp1);
  wprep_kernel<<<64, 256, 0, stream>>>(W2, Wp2);
  wprep_kernel<<<64, 256, 0, stream>>>(W3, Wp3);

  const int AGG_BLOCKS  = (N_NODES + 3) / 4;          // 4 waves/block, 1 node/wave
  const int GEMM_BLOCKS = (N_NODES + 63) / 64;        // 64 rows/block

  // layer 1: x (fp32) -> T -> H (bf16, relu)
  agg_kernel<false><<<AGG_BLOCKS, 256, 0, stream>>>(x, offs, deg, inv_deg, eidx, T);
  gemm_kernel<false, true><<<GEMM_BLOCKS, 256, 0, stream>>>(T, Wp1, b1, H);

  // layer 2: H (bf16) -> T -> H (bf16, relu)
  agg_kernel<true><<<AGG_BLOCKS, 256, 0, stream>>>(H, offs, deg, inv_deg, eidx, T);
  gemm_kernel<false, true><<<GEMM_BLOCKS, 256, 0, stream>>>(T, Wp2, b2, H);

  // layer 3: H (bf16) -> T -> d_out (fp32, no relu)
  agg_kernel<true><<<AGG_BLOCKS, 256, 0, stream>>>(H, offs, deg, inv_deg, eidx, T);
  gemm_kernel<true, false><<<GEMM_BLOCKS, 256, 0, stream>>>(T, Wp3, b3, d_out);

  (void)in_sizes; (void)n_in; (void)out_size; (void)ws_size; (void)w;
}

// Round 2
// 564.820 us; speedup vs baseline: 1.2431x; 1.2431x over previous
//
#include <hip/hip_runtime.h>
#include <hip/hip_bf16.h>
#include <stdint.h>

#define N_NODES 100000
#define N_EDGES 1600000
#define FEAT 128

typedef uint16_t u16;
typedef uint32_t u32;
typedef __attribute__((ext_vector_type(8))) short bf16x8;
typedef __attribute__((ext_vector_type(4))) float f32x4;

__device__ __forceinline__ u16 bf16_rn(float f){
  u32 u = __float_as_uint(f);
  u += 0x7FFFu + ((u >> 16) & 1u);
  return (u16)(u >> 16);
}
__device__ __forceinline__ float bf16_lo(u32 p){ return __uint_as_float(p << 16); }
__device__ __forceinline__ float bf16_hi(u32 p){ return __uint_as_float(p & 0xFFFF0000u); }

// ---------------- CSR build ----------------

__global__ void count_deg_kernel(const int* __restrict__ dst, int* __restrict__ deg){
  int e = blockIdx.x * 256 + threadIdx.x;
  if (e < N_EDGES) atomicAdd(&deg[dst[e]], 1);
}

__global__ void scan_blocks_kernel(const int* __restrict__ deg, int* __restrict__ offs,
                                   int* __restrict__ bsums){
  __shared__ int s[1024];
  int t = threadIdx.x;
  int i = blockIdx.x * 1024 + t;
  int v = (i < N_NODES) ? deg[i] : 0;
  s[t] = v;
  __syncthreads();
  for (int d = 1; d < 1024; d <<= 1){
    int add = (t >= d) ? s[t - d] : 0;
    __syncthreads();
    s[t] += add;
    __syncthreads();
  }
  if (i < N_NODES) offs[i] = s[t] - v;   // exclusive within block
  if (t == 1023) bsums[blockIdx.x] = s[1023];
}

__global__ void scan_sums_kernel(int* __restrict__ bsums, int nb){
  if (threadIdx.x == 0 && blockIdx.x == 0){
    int run = 0;
    for (int b = 0; b < nb; ++b){
      int t = bsums[b];
      bsums[b] = run;
      run += t;
    }
  }
}

__global__ void finalize_kernel(const int* __restrict__ deg, int* __restrict__ offs,
                                const int* __restrict__ bsums, float* __restrict__ inv_deg){
  int i = blockIdx.x * 256 + threadIdx.x;
  if (i < N_NODES){
    offs[i] += bsums[i >> 10];
    float d = (float)deg[i];
    inv_deg[i] = 1.0f / fmaxf(d, 1.0f);
  }
}

__global__ void fill_csr_kernel(const int* __restrict__ src, const int* __restrict__ dst,
                                const int* __restrict__ offs, int* __restrict__ cursor,
                                int* __restrict__ eidx){
  int e = blockIdx.x * 256 + threadIdx.x;
  if (e < N_EDGES){
    int d = dst[e];
    int p = atomicAdd(&cursor[d], 1);
    eidx[offs[d] + p] = src[e];
  }
}

// ---------------- x -> bf16 convert ----------------
__global__ void cvt_bf16_kernel(const float* __restrict__ x, u16* __restrict__ xb){
  int i = blockIdx.x * 256 + threadIdx.x;     // one thread per 4 floats
  float4 v = ((const float4*)x)[i];
  u32 o0 = (u32)bf16_rn(v.x) | ((u32)bf16_rn(v.y) << 16);
  u32 o1 = (u32)bf16_rn(v.z) | ((u32)bf16_rn(v.w) << 16);
  ((uint2*)xb)[i] = make_uint2(o0, o1);
}

// ---------------- W pre-shuffle to B-fragment order ----------------
__global__ void wprep_kernel(const float* __restrict__ W, u16* __restrict__ Wp){
  int idx = blockIdx.x * 256 + threadIdx.x;     // 0..16383
  int j    = idx & 7;
  int lane = (idx >> 3) & 63;
  int t    = idx >> 9;                          // n0*4 + k0
  int k0 = t & 3, n0 = t >> 2;
  int k = k0 * 32 + (lane >> 4) * 8 + j;
  int n = n0 * 16 + (lane & 15);
  Wp[idx] = bf16_rn(W[k * FEAT + n]);
}

// ---------------- aggregation: one wave per dst node, 4 edges per load instr ----------------
// Lane = esub*16 + slice; lane loads 16B (8 bf16 feats, slice) of edge (e4+esub)'s src row.
// Each esub group accumulates a partial sum over its edge subset; xor-shuffle merge at end.
__global__ void agg4_kernel(const u16* __restrict__ hin,
                            const int* __restrict__ offs,
                            const int* __restrict__ deg,
                            const float* __restrict__ inv_deg,
                            const int* __restrict__ eidx,
                            u16* __restrict__ T){
  int node = (int)((blockIdx.x * 256u + threadIdx.x) >> 6);
  if (node >= N_NODES) return;
  int lane  = threadIdx.x & 63;
  int slice = lane & 15;
  int esub  = lane >> 4;
  int start = offs[node];
  int cnt   = deg[node];

  float acc[8];
  #pragma unroll
  for (int j = 0; j < 8; ++j) acc[j] = 0.f;

  for (int base = 0; base < cnt; base += 64){
    int m = cnt - base; if (m > 64) m = 64;
    int myidx = (lane < m) ? eidx[start + base + lane] : 0;
    for (int e4 = 0; e4 < m; e4 += 4){
      int which = e4 + esub;
      int src = __shfl(myidx, which);
      if (which < m){
        uint4 q = *(const uint4*)(hin + (size_t)src * FEAT + slice * 8);
        acc[0] += bf16_lo(q.x); acc[1] += bf16_hi(q.x);
        acc[2] += bf16_lo(q.y); acc[3] += bf16_hi(q.y);
        acc[4] += bf16_lo(q.z); acc[5] += bf16_hi(q.z);
        acc[6] += bf16_lo(q.w); acc[7] += bf16_hi(q.w);
      }
    }
  }

  #pragma unroll
  for (int j = 0; j < 8; ++j){
    float v = acc[j];
    v += __shfl_xor(v, 16);
    v += __shfl_xor(v, 32);
    acc[j] = v;
  }

  if (esub == 0){
    float w = inv_deg[node];
    uint4 s = *(const uint4*)(hin + (size_t)node * FEAT + slice * 8);
    float t0 = bf16_lo(s.x) + w * acc[0];
    float t1 = bf16_hi(s.x) + w * acc[1];
    float t2 = bf16_lo(s.y) + w * acc[2];
    float t3 = bf16_hi(s.y) + w * acc[3];
    float t4 = bf16_lo(s.z) + w * acc[4];
    float t5 = bf16_hi(s.z) + w * acc[5];
    float t6 = bf16_lo(s.w) + w * acc[6];
    float t7 = bf16_hi(s.w) + w * acc[7];
    uint4 o;
    o.x = (u32)bf16_rn(t0) | ((u32)bf16_rn(t1) << 16);
    o.y = (u32)bf16_rn(t2) | ((u32)bf16_rn(t3) << 16);
    o.z = (u32)bf16_rn(t4) | ((u32)bf16_rn(t5) << 16);
    o.w = (u32)bf16_rn(t6) | ((u32)bf16_rn(t7) << 16);
    *(uint4*)(T + (size_t)node * FEAT + slice * 8) = o;
  }
}

// ---------------- GEMM: out = [relu](T @ W + b), per-wave 16x128 strip ----------------
template<bool OUT_F32, bool RELU>
__global__ void gemm_kernel(const u16* __restrict__ T, const u16* __restrict__ Wp,
                            const float* __restrict__ bias, void* __restrict__ out){
  int wave = threadIdx.x >> 6;
  int lane = threadIdx.x & 63;
  int row0 = blockIdx.x * 64 + wave * 16;
  if (row0 >= N_NODES) return;
  int quad = lane >> 4;
  int c    = lane & 15;

  f32x4 acc[8];
  #pragma unroll
  for (int i = 0; i < 8; ++i) acc[i] = (f32x4){0.f, 0.f, 0.f, 0.f};

  const u16* arow = T + (size_t)(row0 + c) * FEAT + quad * 8;
  #pragma unroll
  for (int k0 = 0; k0 < 4; ++k0){
    bf16x8 a = *(const bf16x8*)(arow + k0 * 32);
    #pragma unroll
    for (int n0 = 0; n0 < 8; ++n0){
      bf16x8 b = *(const bf16x8*)(Wp + (((n0 << 2) | k0) * 64 + lane) * 8);
      acc[n0] = __builtin_amdgcn_mfma_f32_16x16x32_bf16(a, b, acc[n0], 0, 0, 0);
    }
  }

  #pragma unroll
  for (int n0 = 0; n0 < 8; ++n0){
    float bv = bias[n0 * 16 + c];
    #pragma unroll
    for (int r = 0; r < 4; ++r){
      int row = row0 + quad * 4 + r;
      int col = n0 * 16 + c;
      float v = acc[n0][r] + bv;
      if (RELU) v = fmaxf(v, 0.f);
      if (OUT_F32) ((float*)out)[(size_t)row * FEAT + col] = v;
      else         ((u16*)out)[(size_t)row * FEAT + col]   = bf16_rn(v);
    }
  }
}

// ---------------- launch ----------------

static inline size_t align_up(size_t x){ return (x + 255) & ~(size_t)255; }

extern "C" void kernel_launch(void* const* d_in, const int* in_sizes, int n_in,
                              void* d_out, int out_size, void* d_ws, size_t ws_size,
                              hipStream_t stream){
  const float* x  = (const float*)d_in[0];
  const float* W1 = (const float*)d_in[1];
  const float* b1 = (const float*)d_in[2];
  const float* W2 = (const float*)d_in[3];
  const float* b2 = (const float*)d_in[4];
  const float* W3 = (const float*)d_in[5];
  const float* b3 = (const float*)d_in[6];
  const int* esrc = (const int*)d_in[7];
  const int* edst = (const int*)d_in[8];

  char* w = (char*)d_ws;
  int*   deg     = (int*)w;    w += align_up((size_t)N_NODES * 4);
  int*   offs    = (int*)w;    w += align_up((size_t)(N_NODES + 1) * 4);
  int*   cursor  = (int*)w;    w += align_up((size_t)N_NODES * 4);
  int*   bsums   = (int*)w;    w += align_up(1024 * 4);
  float* inv_deg = (float*)w;  w += align_up((size_t)N_NODES * 4);
  int*   eidx    = (int*)w;    w += align_up((size_t)N_EDGES * 4);
  u16*   Wp1     = (u16*)w;    w += align_up((size_t)16384 * 2);
  u16*   Wp2     = (u16*)w;    w += align_up((size_t)16384 * 2);
  u16*   Wp3     = (u16*)w;    w += align_up((size_t)16384 * 2);
  u16*   T       = (u16*)w;    w += align_up((size_t)N_NODES * FEAT * 2);

  // d_out (51.2 MB fp32) hosts two dead-on-exit bf16 buffers:
  //   H  = lower 25.6 MB (layer-1/2 activations)
  //   Xb = upper 25.6 MB (bf16 copy of x, dead after layer-1 agg)
  u16* H  = (u16*)d_out;
  u16* Xb = (u16*)d_out + (size_t)N_NODES * FEAT;

  hipMemsetAsync(deg,    0, (size_t)N_NODES * 4, stream);
  hipMemsetAsync(cursor, 0, (size_t)N_NODES * 4, stream);

  const int EB = (N_EDGES + 255) / 256;
  const int NB_SCAN = (N_NODES + 1023) / 1024;   // 98

  count_deg_kernel<<<EB, 256, 0, stream>>>(edst, deg);
  scan_blocks_kernel<<<NB_SCAN, 1024, 0, stream>>>(deg, offs, bsums);
  scan_sums_kernel<<<1, 64, 0, stream>>>(bsums, NB_SCAN);
  finalize_kernel<<<(N_NODES + 255) / 256, 256, 0, stream>>>(deg, offs, bsums, inv_deg);
  fill_csr_kernel<<<EB, 256, 0, stream>>>(esrc, edst, offs, cursor, eidx);

  cvt_bf16_kernel<<<(N_NODES * FEAT / 4 + 255) / 256, 256, 0, stream>>>(x, Xb);
  wprep_kernel<<<64, 256, 0, stream>>>(W1, Wp1);
  wprep_kernel<<<64, 256, 0, stream>>>(W2, Wp2);
  wprep_kernel<<<64, 256, 0, stream>>>(W3, Wp3);

  const int AGG_BLOCKS  = (N_NODES + 3) / 4;          // 4 waves/block, 1 node/wave
  const int GEMM_BLOCKS = (N_NODES + 63) / 64;        // 64 rows/block

  // layer 1: Xb (bf16) -> T -> H (bf16, relu)
  agg4_kernel<<<AGG_BLOCKS, 256, 0, stream>>>(Xb, offs, deg, inv_deg, eidx, T);
  gemm_kernel<false, true><<<GEMM_BLOCKS, 256, 0, stream>>>(T, Wp1, b1, H);

  // layer 2: H (bf16) -> T -> H (bf16, relu)
  agg4_kernel<<<AGG_BLOCKS, 256, 0, stream>>>(H, offs, deg, inv_deg, eidx, T);
  gemm_kernel<false, true><<<GEMM_BLOCKS, 256, 0, stream>>>(T, Wp2, b2, H);

  // layer 3: H (bf16) -> T -> d_out (fp32, no relu)
  agg4_kernel<<<AGG_BLOCKS, 256, 0, stream>>>(H, offs, deg, inv_deg, eidx, T);
  gemm_kernel<true, false><<<GEMM_BLOCKS, 256, 0, stream>>>(T, Wp3, b3, d_out);

  (void)in_sizes; (void)n_in; (void)out_size; (void)ws_size; (void)w;
}

// Round 3
// 440.888 us; speedup vs baseline: 1.5925x; 1.2811x over previous
//
#include <hip/hip_runtime.h>
#include <hip/hip_bf16.h>
#include <stdint.h>

#define N_NODES 100000
#define N_EDGES 1600000
#define FEAT 128

#define BKT_SHIFT 8
#define BKT_SIZE  256
#define NB_BKT    391          // ceil(N_NODES / 256)
#define NB_A      400          // blocks in edge passes
#define EPB       4000         // edges per block (400*4000 = 1.6M)

typedef uint16_t u16;
typedef uint32_t u32;
typedef __attribute__((ext_vector_type(8))) short bf16x8;
typedef __attribute__((ext_vector_type(4))) float f32x4;

__device__ __forceinline__ u16 bf16_rn(float f){
  u32 u = __float_as_uint(f);
  u += 0x7FFFu + ((u >> 16) & 1u);
  return (u16)(u >> 16);
}
__device__ __forceinline__ float bf16_lo(u32 p){ return __uint_as_float(p << 16); }
__device__ __forceinline__ float bf16_hi(u32 p){ return __uint_as_float(p & 0xFFFF0000u); }

// ---------------- CSR build via two-level counting sort ----------------

__global__ void bucket_hist_kernel(const int* __restrict__ dst, int* __restrict__ bcnt){
  __shared__ int h[NB_BKT];
  for (int i = threadIdx.x; i < NB_BKT; i += 256) h[i] = 0;
  __syncthreads();
  int base = blockIdx.x * EPB;
  int end  = min(base + EPB, N_EDGES);
  for (int e = base + threadIdx.x; e < end; e += 256)
    atomicAdd(&h[dst[e] >> BKT_SHIFT], 1);
  __syncthreads();
  for (int i = threadIdx.x; i < NB_BKT; i += 256)
    if (h[i]) atomicAdd(&bcnt[i], h[i]);
}

__global__ void bucket_scan_kernel(const int* __restrict__ bcnt, int* __restrict__ bbase,
                                   int* __restrict__ bcur){
  __shared__ int s[512];
  int t = threadIdx.x;
  int v = (t < NB_BKT) ? bcnt[t] : 0;
  s[t] = v;
  __syncthreads();
  for (int d = 1; d < 512; d <<= 1){
    int u = (t >= d) ? s[t - d] : 0;
    __syncthreads();
    s[t] += u;
    __syncthreads();
  }
  if (t < NB_BKT){
    int excl = s[t] - v;
    bbase[t] = excl;
    bcur[t]  = excl;
  }
  if (t == NB_BKT - 1) bbase[NB_BKT] = s[t];
}

__global__ void bucket_scatter_kernel(const int* __restrict__ src, const int* __restrict__ dst,
                                      int* __restrict__ bcur, uint2* __restrict__ bbuf){
  __shared__ int h[NB_BKT];
  __shared__ int res[NB_BKT];
  for (int i = threadIdx.x; i < NB_BKT; i += 256) h[i] = 0;
  __syncthreads();
  int base = blockIdx.x * EPB;
  int end  = min(base + EPB, N_EDGES);
  for (int e = base + threadIdx.x; e < end; e += 256)
    atomicAdd(&h[dst[e] >> BKT_SHIFT], 1);
  __syncthreads();
  for (int i = threadIdx.x; i < NB_BKT; i += 256){
    int c = h[i];
    res[i] = c ? atomicAdd(&bcur[i], c) : 0;
    h[i] = 0;                       // reuse as local cursor
  }
  __syncthreads();
  for (int e = base + threadIdx.x; e < end; e += 256){
    int d = dst[e];
    int b = d >> BKT_SHIFT;
    int p = atomicAdd(&h[b], 1);
    bbuf[res[b] + p] = make_uint2((u32)src[e], (u32)(d & (BKT_SIZE - 1)));
  }
}

// one block per bucket: per-node LDS histogram + scan + LDS-atomic scatter
__global__ void csr_build_kernel(const uint2* __restrict__ bbuf, const int* __restrict__ bbase,
                                 int* __restrict__ offs, int* __restrict__ deg,
                                 float* __restrict__ inv_deg, int* __restrict__ eidx){
  __shared__ int hist[BKT_SIZE];
  __shared__ int s[BKT_SIZE];
  __shared__ int cu[BKT_SIZE];
  int b = blockIdx.x;
  int t = threadIdx.x;
  int lo = bbase[b], hi = bbase[b + 1];
  hist[t] = 0;
  __syncthreads();
  for (int e = lo + t; e < hi; e += BKT_SIZE)
    atomicAdd(&hist[bbuf[e].y], 1);
  __syncthreads();
  int v = hist[t];
  s[t] = v;
  __syncthreads();
  for (int d = 1; d < BKT_SIZE; d <<= 1){
    int u = (t >= d) ? s[t - d] : 0;
    __syncthreads();
    s[t] += u;
    __syncthreads();
  }
  int excl = s[t] - v;
  int node = b * BKT_SIZE + t;
  if (node < N_NODES){
    offs[node]    = lo + excl;
    deg[node]     = v;
    inv_deg[node] = 1.0f / fmaxf((float)v, 1.0f);
  }
  __syncthreads();
  s[t]  = excl;
  cu[t] = 0;
  __syncthreads();
  for (int e = lo + t; e < hi; e += BKT_SIZE){
    uint2 q = bbuf[e];
    int p = atomicAdd(&cu[q.y], 1);
    eidx[lo + s[q.y] + p] = (int)q.x;
  }
}

// ---------------- x -> bf16 convert ----------------
__global__ void cvt_bf16_kernel(const float* __restrict__ x, u16* __restrict__ xb){
  int i = blockIdx.x * 256 + threadIdx.x;     // one thread per 4 floats
  float4 v = ((const float4*)x)[i];
  u32 o0 = (u32)bf16_rn(v.x) | ((u32)bf16_rn(v.y) << 16);
  u32 o1 = (u32)bf16_rn(v.z) | ((u32)bf16_rn(v.w) << 16);
  ((uint2*)xb)[i] = make_uint2(o0, o1);
}

// ---------------- W pre-shuffle to B-fragment order ----------------
__global__ void wprep_kernel(const float* __restrict__ W, u16* __restrict__ Wp){
  int idx = blockIdx.x * 256 + threadIdx.x;     // 0..16383
  int j    = idx & 7;
  int lane = (idx >> 3) & 63;
  int t    = idx >> 9;                          // n0*4 + k0
  int k0 = t & 3, n0 = t >> 2;
  int k = k0 * 32 + (lane >> 4) * 8 + j;
  int n = n0 * 16 + (lane & 15);
  Wp[idx] = bf16_rn(W[k * FEAT + n]);
}

// ---------------- aggregation: one wave per dst node, 4 edges per load instr ----------------
__global__ void agg4_kernel(const u16* __restrict__ hin,
                            const int* __restrict__ offs,
                            const int* __restrict__ deg,
                            const float* __restrict__ inv_deg,
                            const int* __restrict__ eidx,
                            u16* __restrict__ T){
  int node = (int)((blockIdx.x * 256u + threadIdx.x) >> 6);
  if (node >= N_NODES) return;
  int lane  = threadIdx.x & 63;
  int slice = lane & 15;
  int esub  = lane >> 4;
  int start = offs[node];
  int cnt   = deg[node];

  float acc[8];
  #pragma unroll
  for (int j = 0; j < 8; ++j) acc[j] = 0.f;

  for (int base = 0; base < cnt; base += 64){
    int m = cnt - base; if (m > 64) m = 64;
    int myidx = (lane < m) ? eidx[start + base + lane] : 0;
    for (int e4 = 0; e4 < m; e4 += 4){
      int which = e4 + esub;
      int src = __shfl(myidx, which);
      if (which < m){
        uint4 q = *(const uint4*)(hin + (size_t)src * FEAT + slice * 8);
        acc[0] += bf16_lo(q.x); acc[1] += bf16_hi(q.x);
        acc[2] += bf16_lo(q.y); acc[3] += bf16_hi(q.y);
        acc[4] += bf16_lo(q.z); acc[5] += bf16_hi(q.z);
        acc[6] += bf16_lo(q.w); acc[7] += bf16_hi(q.w);
      }
    }
  }

  #pragma unroll
  for (int j = 0; j < 8; ++j){
    float v = acc[j];
    v += __shfl_xor(v, 16);
    v += __shfl_xor(v, 32);
    acc[j] = v;
  }

  if (esub == 0){
    float w = inv_deg[node];
    uint4 s = *(const uint4*)(hin + (size_t)node * FEAT + slice * 8);
    float t0 = bf16_lo(s.x) + w * acc[0];
    float t1 = bf16_hi(s.x) + w * acc[1];
    float t2 = bf16_lo(s.y) + w * acc[2];
    float t3 = bf16_hi(s.y) + w * acc[3];
    float t4 = bf16_lo(s.z) + w * acc[4];
    float t5 = bf16_hi(s.z) + w * acc[5];
    float t6 = bf16_lo(s.w) + w * acc[6];
    float t7 = bf16_hi(s.w) + w * acc[7];
    uint4 o;
    o.x = (u32)bf16_rn(t0) | ((u32)bf16_rn(t1) << 16);
    o.y = (u32)bf16_rn(t2) | ((u32)bf16_rn(t3) << 16);
    o.z = (u32)bf16_rn(t4) | ((u32)bf16_rn(t5) << 16);
    o.w = (u32)bf16_rn(t6) | ((u32)bf16_rn(t7) << 16);
    *(uint4*)(T + (size_t)node * FEAT + slice * 8) = o;
  }
}

// ---------------- GEMM: out = [relu](T @ W + b), per-wave 16x128 strip ----------------
template<bool OUT_F32, bool RELU>
__global__ void gemm_kernel(const u16* __restrict__ T, const u16* __restrict__ Wp,
                            const float* __restrict__ bias, void* __restrict__ out){
  int wave = threadIdx.x >> 6;
  int lane = threadIdx.x & 63;
  int row0 = blockIdx.x * 64 + wave * 16;
  if (row0 >= N_NODES) return;
  int quad = lane >> 4;
  int c    = lane & 15;

  f32x4 acc[8];
  #pragma unroll
  for (int i = 0; i < 8; ++i) acc[i] = (f32x4){0.f, 0.f, 0.f, 0.f};

  const u16* arow = T + (size_t)(row0 + c) * FEAT + quad * 8;
  #pragma unroll
  for (int k0 = 0; k0 < 4; ++k0){
    bf16x8 a = *(const bf16x8*)(arow + k0 * 32);
    #pragma unroll
    for (int n0 = 0; n0 < 8; ++n0){
      bf16x8 b = *(const bf16x8*)(Wp + (((n0 << 2) | k0) * 64 + lane) * 8);
      acc[n0] = __builtin_amdgcn_mfma_f32_16x16x32_bf16(a, b, acc[n0], 0, 0, 0);
    }
  }

  #pragma unroll
  for (int n0 = 0; n0 < 8; ++n0){
    float bv = bias[n0 * 16 + c];
    #pragma unroll
    for (int r = 0; r < 4; ++r){
      int row = row0 + quad * 4 + r;
      int col = n0 * 16 + c;
      float v = acc[n0][r] + bv;
      if (RELU) v = fmaxf(v, 0.f);
      if (OUT_F32) ((float*)out)[(size_t)row * FEAT + col] = v;
      else         ((u16*)out)[(size_t)row * FEAT + col]   = bf16_rn(v);
    }
  }
}

// ---------------- launch ----------------

static inline size_t align_up(size_t x){ return (x + 255) & ~(size_t)255; }

extern "C" void kernel_launch(void* const* d_in, const int* in_sizes, int n_in,
                              void* d_out, int out_size, void* d_ws, size_t ws_size,
                              hipStream_t stream){
  const float* x  = (const float*)d_in[0];
  const float* W1 = (const float*)d_in[1];
  const float* b1 = (const float*)d_in[2];
  const float* W2 = (const float*)d_in[3];
  const float* b2 = (const float*)d_in[4];
  const float* W3 = (const float*)d_in[5];
  const float* b3 = (const float*)d_in[6];
  const int* esrc = (const int*)d_in[7];
  const int* edst = (const int*)d_in[8];

  char* w = (char*)d_ws;
  int*   bcnt    = (int*)w;    w += align_up((size_t)(NB_BKT + 1) * 4);
  int*   bbase   = (int*)w;    w += align_up((size_t)(NB_BKT + 1) * 4);
  int*   bcur    = (int*)w;    w += align_up((size_t)(NB_BKT + 1) * 4);
  int*   deg     = (int*)w;    w += align_up((size_t)N_NODES * 4);
  int*   offs    = (int*)w;    w += align_up((size_t)N_NODES * 4);
  float* inv_deg = (float*)w;  w += align_up((size_t)N_NODES * 4);
  int*   eidx    = (int*)w;    w += align_up((size_t)N_EDGES * 4);
  u16*   Wp1     = (u16*)w;    w += align_up((size_t)16384 * 2);
  u16*   Wp2     = (u16*)w;    w += align_up((size_t)16384 * 2);
  u16*   Wp3     = (u16*)w;    w += align_up((size_t)16384 * 2);
  u16*   T       = (u16*)w;    w += align_up((size_t)N_NODES * FEAT * 2);

  // bucket buffer (12.8 MB) aliases T (25.6 MB) — T is dead during CSR build
  uint2* bbuf = (uint2*)T;

  // d_out (51.2 MB fp32) hosts two dead-on-exit bf16 buffers
  u16* H  = (u16*)d_out;
  u16* Xb = (u16*)d_out + (size_t)N_NODES * FEAT;

  hipMemsetAsync(bcnt, 0, (size_t)(NB_BKT + 1) * 4, stream);

  // CSR build: two-level counting sort
  bucket_hist_kernel<<<NB_A, 256, 0, stream>>>(edst, bcnt);
  bucket_scan_kernel<<<1, 512, 0, stream>>>(bcnt, bbase, bcur);
  bucket_scatter_kernel<<<NB_A, 256, 0, stream>>>(esrc, edst, bcur, bbuf);
  csr_build_kernel<<<NB_BKT, BKT_SIZE, 0, stream>>>(bbuf, bbase, offs, deg, inv_deg, eidx);

  cvt_bf16_kernel<<<(N_NODES * FEAT / 4 + 255) / 256, 256, 0, stream>>>(x, Xb);
  wprep_kernel<<<64, 256, 0, stream>>>(W1, Wp1);
  wprep_kernel<<<64, 256, 0, stream>>>(W2, Wp2);
  wprep_kernel<<<64, 256, 0, stream>>>(W3, Wp3);

  const int AGG_BLOCKS  = (N_NODES + 3) / 4;
  const int GEMM_BLOCKS = (N_NODES + 63) / 64;

  // layer 1: Xb (bf16) -> T -> H (bf16, relu)
  agg4_kernel<<<AGG_BLOCKS, 256, 0, stream>>>(Xb, offs, deg, inv_deg, eidx, T);
  gemm_kernel<false, true><<<GEMM_BLOCKS, 256, 0, stream>>>(T, Wp1, b1, H);

  // layer 2: H (bf16) -> T -> H (bf16, relu)
  agg4_kernel<<<AGG_BLOCKS, 256, 0, stream>>>(H, offs, deg, inv_deg, eidx, T);
  gemm_kernel<false, true><<<GEMM_BLOCKS, 256, 0, stream>>>(T, Wp2, b2, H);

  // layer 3: H (bf16) -> T -> d_out (fp32, no relu)
  agg4_kernel<<<AGG_BLOCKS, 256, 0, stream>>>(H, offs, deg, inv_deg, eidx, T);
  gemm_kernel<true, false><<<GEMM_BLOCKS, 256, 0, stream>>>(T, Wp3, b3, d_out);

  (void)in_sizes; (void)n_in; (void)out_size; (void)ws_size; (void)w;
}

// Round 4
// 427.140 us; speedup vs baseline: 1.6438x; 1.0322x over previous
//
#include <hip/hip_runtime.h>
#include <hip/hip_bf16.h>
#include <stdint.h>

#if __has_builtin(__builtin_amdgcn_cvt_pk_f32_fp8) && __has_builtin(__builtin_amdgcn_cvt_pk_fp8_f32)
#define FP8_HW 1
#else
#define FP8_HW 0
#include <hip/hip_fp8.h>
#endif

#define N_NODES 100000
#define N_EDGES 1600000
#define FEAT 128

#define BKT_SHIFT 8
#define BKT_SIZE  256
#define NB_BKT    391          // ceil(N_NODES / 256)
#define BKT_CAP   4864         // expected 4096, sigma 64; 12-sigma headroom (fixed graph)
#define NB_A      400          // blocks in edge passes
#define EPB       4000         // edges per block

typedef uint16_t u16;
typedef uint32_t u32;
typedef __attribute__((ext_vector_type(8))) short bf16x8;
typedef __attribute__((ext_vector_type(4))) float f32x4;
typedef __attribute__((ext_vector_type(2))) float f32x2;

__device__ __forceinline__ u16 bf16_rn(float f){
  u32 u = __float_as_uint(f);
  u += 0x7FFFu + ((u >> 16) & 1u);
  return (u16)(u >> 16);
}
__device__ __forceinline__ float bf16_lo(u32 p){ return __uint_as_float(p << 16); }
__device__ __forceinline__ float bf16_hi(u32 p){ return __uint_as_float(p & 0xFFFF0000u); }

__device__ __forceinline__ void fp8x4_to_f32(u32 w, float* o){
#if FP8_HW
  f32x2 a = __builtin_amdgcn_cvt_pk_f32_fp8(w, false);
  f32x2 b = __builtin_amdgcn_cvt_pk_f32_fp8(w, true);
  o[0] = a.x; o[1] = a.y; o[2] = b.x; o[3] = b.y;
#else
  #pragma unroll
  for (int i = 0; i < 4; ++i){
    __hip_fp8_e4m3 t; t.__x = (uint8_t)((w >> (8 * i)) & 0xFF);
    o[i] = (float)t;
  }
#endif
}
__device__ __forceinline__ u32 f32x4_to_fp8(float a, float b, float c, float d){
#if FP8_HW
  u32 r = __builtin_amdgcn_cvt_pk_fp8_f32(a, b, 0, false);
  r = __builtin_amdgcn_cvt_pk_fp8_f32(c, d, r, true);
  return r;
#else
  __hip_fp8_e4m3 qa(a), qb(b), qc(c), qd(d);
  return (u32)qa.__x | ((u32)qb.__x << 8) | ((u32)qc.__x << 16) | ((u32)qd.__x << 24);
#endif
}

// ---------------- CSR build: fixed-capacity bucket scatter + per-bucket sort ----------------

__global__ void bucket_scatter_kernel(const int* __restrict__ src, const int* __restrict__ dst,
                                      int* __restrict__ cursor, uint2* __restrict__ bbuf){
  __shared__ int h[NB_BKT];
  __shared__ int res[NB_BKT];
  for (int i = threadIdx.x; i < NB_BKT; i += 256) h[i] = 0;
  __syncthreads();
  int base = blockIdx.x * EPB;
  int end  = min(base + EPB, N_EDGES);
  for (int e = base + threadIdx.x; e < end; e += 256)
    atomicAdd(&h[dst[e] >> BKT_SHIFT], 1);
  __syncthreads();
  for (int i = threadIdx.x; i < NB_BKT; i += 256){
    int c = h[i];
    res[i] = c ? atomicAdd(&cursor[i], c) : 0;
    h[i] = 0;                       // reuse as local cursor
  }
  __syncthreads();
  for (int e = base + threadIdx.x; e < end; e += 256){
    int d = dst[e];
    int b = d >> BKT_SHIFT;
    int p = atomicAdd(&h[b], 1);
    bbuf[(size_t)b * BKT_CAP + res[b] + p] = make_uint2((u32)src[e], (u32)(d & (BKT_SIZE - 1)));
  }
}

__global__ void csr_build_kernel(const uint2* __restrict__ bbuf, const int* __restrict__ cursor,
                                 int* __restrict__ offs, int* __restrict__ deg,
                                 float* __restrict__ inv_deg, int* __restrict__ eidx){
  __shared__ int hist[BKT_SIZE];
  __shared__ int s[BKT_SIZE];
  __shared__ int cu[BKT_SIZE];
  int b = blockIdx.x;
  int t = threadIdx.x;
  int lo = b * BKT_CAP;
  int hi = lo + cursor[b];
  hist[t] = 0;
  __syncthreads();
  for (int e = lo + t; e < hi; e += BKT_SIZE)
    atomicAdd(&hist[bbuf[e].y], 1);
  __syncthreads();
  int v = hist[t];
  s[t] = v;
  __syncthreads();
  for (int d = 1; d < BKT_SIZE; d <<= 1){
    int u = (t >= d) ? s[t - d] : 0;
    __syncthreads();
    s[t] += u;
    __syncthreads();
  }
  int excl = s[t] - v;
  int node = b * BKT_SIZE + t;
  if (node < N_NODES){
    offs[node]    = lo + excl;
    deg[node]     = v;
    inv_deg[node] = 1.0f / fmaxf((float)v, 1.0f);
  }
  __syncthreads();
  s[t]  = excl;
  cu[t] = 0;
  __syncthreads();
  for (int e = lo + t; e < hi; e += BKT_SIZE){
    uint2 q = bbuf[e];
    int p = atomicAdd(&cu[q.y], 1);
    eidx[lo + s[q.y] + p] = (int)q.x;
  }
}

// ---------------- conversions ----------------

// x (fp32) -> X8 (fp8): one thread per 8 elems
__global__ void cvt_x8_kernel(const float* __restrict__ x, uint2* __restrict__ X8){
  int i = blockIdx.x * 256 + threadIdx.x;        // < 1.6M
  const float4* p = (const float4*)x + (size_t)i * 2;
  float4 a = p[0], b = p[1];
  uint2 o;
  o.x = f32x4_to_fp8(a.x, a.y, a.z, a.w);
  o.y = f32x4_to_fp8(b.x, b.y, b.z, b.w);
  X8[i] = o;
}

// H (bf16) -> H8 (fp8): one thread per 8 elems
__global__ void cvt_h8_kernel(const u16* __restrict__ H, uint2* __restrict__ H8){
  int i = blockIdx.x * 256 + threadIdx.x;        // < 1.6M
  uint4 hq = ((const uint4*)H)[i];
  uint2 o;
  o.x = f32x4_to_fp8(bf16_lo(hq.x), bf16_hi(hq.x), bf16_lo(hq.y), bf16_hi(hq.y));
  o.y = f32x4_to_fp8(bf16_lo(hq.z), bf16_hi(hq.z), bf16_lo(hq.w), bf16_hi(hq.w));
  H8[i] = o;
}

// W pre-shuffle, all three weights in one launch (192 blocks)
__global__ void wprep3_kernel(const float* __restrict__ W1, const float* __restrict__ W2,
                              const float* __restrict__ W3, u16* __restrict__ Wp1,
                              u16* __restrict__ Wp2, u16* __restrict__ Wp3){
  int which = blockIdx.x >> 6;
  int b     = blockIdx.x & 63;
  const float* W = (which == 0) ? W1 : (which == 1) ? W2 : W3;
  u16*        Wp = (which == 0) ? Wp1 : (which == 1) ? Wp2 : Wp3;
  int idx = b * 256 + threadIdx.x;              // 0..16383
  int j    = idx & 7;
  int lane = (idx >> 3) & 63;
  int t    = idx >> 9;
  int k0 = t & 3, n0 = t >> 2;
  int k = k0 * 32 + (lane >> 4) * 8 + j;
  int n = n0 * 16 + (lane & 15);
  Wp[idx] = bf16_rn(W[k * FEAT + n]);
}

// ---------------- aggregation: fp8 neighbors, 8 edges per wave-instruction ----------------
// lane = esub*8 + slice; esub in 0..7 = edge subgroup, slice in 0..7 = 16-feat chunk.
// T[dst] = self[dst] + inv_deg[dst] * sum fp8(h[src]); self from bf16 H (SM=0) or fp32 x (SM=1).
template<int SM>
__global__ void agg8_kernel(const u32* __restrict__ n8,     // fp8 table, row = 32 u32
                            const u16* __restrict__ hb,     // bf16 self table (SM=0)
                            const float* __restrict__ xf,   // fp32 self table (SM=1)
                            const int* __restrict__ offs,
                            const int* __restrict__ deg,
                            const float* __restrict__ inv_deg,
                            const int* __restrict__ eidx,
                            u16* __restrict__ T){
  int node = (int)((blockIdx.x * 256u + threadIdx.x) >> 6);
  if (node >= N_NODES) return;
  int lane  = threadIdx.x & 63;
  int slice = lane & 7;
  int esub  = lane >> 3;
  int start = offs[node];
  int cnt   = deg[node];
  const int* ep = eidx + start;

  float acc[16];
  #pragma unroll
  for (int j = 0; j < 16; ++j) acc[j] = 0.f;

  // prefetched indices for edge groups e+esub and e+8+esub; masked lanes -> row 0, weight 0
  int a0 = (esub < cnt) ? esub : 0;
  int a1 = (8 + esub < cnt) ? 8 + esub : 0;
  float f0 = (esub < cnt) ? 1.f : 0.f;
  float f1 = (8 + esub < cnt) ? 1.f : 0.f;
  int i0 = ep[a0]; if (f0 == 0.f) i0 = 0;
  int i1 = ep[a1]; if (f1 == 0.f) i1 = 0;

  for (int e = 0; e < cnt; e += 16){
    int b0 = e + 16 + esub, b1 = e + 24 + esub;
    int n0 = ep[(b0 < cnt) ? b0 : 0];
    int n1 = ep[(b1 < cnt) ? b1 : 0];
    float g0 = (b0 < cnt) ? 1.f : 0.f;
    float g1 = (b1 < cnt) ? 1.f : 0.f;
    if (g0 == 0.f) n0 = 0;
    if (g1 == 0.f) n1 = 0;
    uint4 q0 = *(const uint4*)(n8 + (size_t)i0 * 32 + slice * 4);
    uint4 q1 = *(const uint4*)(n8 + (size_t)i1 * 32 + slice * 4);
    float tf[4];
    fp8x4_to_f32(q0.x, tf); acc[0]+=f0*tf[0]; acc[1]+=f0*tf[1]; acc[2] +=f0*tf[2]; acc[3] +=f0*tf[3];
    fp8x4_to_f32(q0.y, tf); acc[4]+=f0*tf[0]; acc[5]+=f0*tf[1]; acc[6] +=f0*tf[2]; acc[7] +=f0*tf[3];
    fp8x4_to_f32(q0.z, tf); acc[8]+=f0*tf[0]; acc[9]+=f0*tf[1]; acc[10]+=f0*tf[2]; acc[11]+=f0*tf[3];
    fp8x4_to_f32(q0.w, tf); acc[12]+=f0*tf[0]; acc[13]+=f0*tf[1]; acc[14]+=f0*tf[2]; acc[15]+=f0*tf[3];
    fp8x4_to_f32(q1.x, tf); acc[0]+=f1*tf[0]; acc[1]+=f1*tf[1]; acc[2] +=f1*tf[2]; acc[3] +=f1*tf[3];
    fp8x4_to_f32(q1.y, tf); acc[4]+=f1*tf[0]; acc[5]+=f1*tf[1]; acc[6] +=f1*tf[2]; acc[7] +=f1*tf[3];
    fp8x4_to_f32(q1.z, tf); acc[8]+=f1*tf[0]; acc[9]+=f1*tf[1]; acc[10]+=f1*tf[2]; acc[11]+=f1*tf[3];
    fp8x4_to_f32(q1.w, tf); acc[12]+=f1*tf[0]; acc[13]+=f1*tf[1]; acc[14]+=f1*tf[2]; acc[15]+=f1*tf[3];
    i0 = n0; i1 = n1; f0 = g0; f1 = g1;
  }

  // reduce across esub (lane bits 3..5)
  #pragma unroll
  for (int j = 0; j < 16; ++j){
    float v = acc[j];
    v += __shfl_xor(v, 8);
    v += __shfl_xor(v, 16);
    v += __shfl_xor(v, 32);
    acc[j] = v;
  }

  if (esub == 0){
    float w = inv_deg[node];
    float self[16];
    if (SM == 1){
      const float* sp = xf + (size_t)node * FEAT + slice * 16;
      #pragma unroll
      for (int g = 0; g < 4; ++g){
        float4 v = *(const float4*)(sp + g * 4);
        self[g*4+0] = v.x; self[g*4+1] = v.y; self[g*4+2] = v.z; self[g*4+3] = v.w;
      }
    } else {
      const u16* sp = hb + (size_t)node * FEAT + slice * 16;
      uint4 s0 = *(const uint4*)sp;
      uint4 s1 = *(const uint4*)(sp + 8);
      self[0]=bf16_lo(s0.x); self[1]=bf16_hi(s0.x); self[2]=bf16_lo(s0.y); self[3]=bf16_hi(s0.y);
      self[4]=bf16_lo(s0.z); self[5]=bf16_hi(s0.z); self[6]=bf16_lo(s0.w); self[7]=bf16_hi(s0.w);
      self[8]=bf16_lo(s1.x); self[9]=bf16_hi(s1.x); self[10]=bf16_lo(s1.y); self[11]=bf16_hi(s1.y);
      self[12]=bf16_lo(s1.z); self[13]=bf16_hi(s1.z); self[14]=bf16_lo(s1.w); self[15]=bf16_hi(s1.w);
    }
    u32 o[8];
    #pragma unroll
    for (int jj = 0; jj < 8; ++jj){
      float t0 = self[2*jj]   + w * acc[2*jj];
      float t1 = self[2*jj+1] + w * acc[2*jj+1];
      o[jj] = (u32)bf16_rn(t0) | ((u32)bf16_rn(t1) << 16);
    }
    u16* op = T + (size_t)node * FEAT + slice * 16;
    *(uint4*)op       = make_uint4(o[0], o[1], o[2], o[3]);
    *(uint4*)(op + 8) = make_uint4(o[4], o[5], o[6], o[7]);
  }
}

// ---------------- GEMM: 32 rows/wave (2 tiles share B fragments), 128 rows/block ----------------
template<int MODE>   // 0: bf16 + relu; 1: fp32, no relu
__global__ __launch_bounds__(256) void gemm2_kernel(const u16* __restrict__ T,
                                                    const u16* __restrict__ Wp,
                                                    const float* __restrict__ bias,
                                                    void* __restrict__ out){
  int wave = threadIdx.x >> 6;
  int lane = threadIdx.x & 63;
  int row0 = blockIdx.x * 128 + wave * 32;
  if (row0 >= N_NODES) return;
  int quad = lane >> 4;
  int c    = lane & 15;

  f32x4 acc[2][8];
  #pragma unroll
  for (int t = 0; t < 2; ++t)
    #pragma unroll
    for (int i = 0; i < 8; ++i) acc[t][i] = (f32x4){0.f, 0.f, 0.f, 0.f};

  bf16x8 A[2][4];
  const u16* ar0 = T + (size_t)(row0 + c) * FEAT + quad * 8;
  const u16* ar1 = ar0 + 16 * FEAT;
  #pragma unroll
  for (int k0 = 0; k0 < 4; ++k0){
    A[0][k0] = *(const bf16x8*)(ar0 + k0 * 32);
    A[1][k0] = *(const bf16x8*)(ar1 + k0 * 32);
  }

  #pragma unroll
  for (int n0 = 0; n0 < 8; ++n0){
    #pragma unroll
    for (int k0 = 0; k0 < 4; ++k0){
      bf16x8 b = *(const bf16x8*)(Wp + (((n0 << 2) | k0) * 64 + lane) * 8);
      acc[0][n0] = __builtin_amdgcn_mfma_f32_16x16x32_bf16(A[0][k0], b, acc[0][n0], 0, 0, 0);
      acc[1][n0] = __builtin_amdgcn_mfma_f32_16x16x32_bf16(A[1][k0], b, acc[1][n0], 0, 0, 0);
    }
  }

  #pragma unroll
  for (int t = 0; t < 2; ++t){
    #pragma unroll
    for (int n0 = 0; n0 < 8; ++n0){
      float bv = bias[n0 * 16 + c];
      #pragma unroll
      for (int r = 0; r < 4; ++r){
        int row = row0 + t * 16 + quad * 4 + r;
        int col = n0 * 16 + c;
        float v = acc[t][n0][r] + bv;
        if (MODE == 0){
          v = fmaxf(v, 0.f);
          ((u16*)out)[(size_t)row * FEAT + col] = bf16_rn(v);
        } else {
          ((float*)out)[(size_t)row * FEAT + col] = v;
        }
      }
    }
  }
}

// ---------------- launch ----------------

static inline size_t align_up(size_t x){ return (x + 255) & ~(size_t)255; }

extern "C" void kernel_launch(void* const* d_in, const int* in_sizes, int n_in,
                              void* d_out, int out_size, void* d_ws, size_t ws_size,
                              hipStream_t stream){
  const float* x  = (const float*)d_in[0];
  const float* W1 = (const float*)d_in[1];
  const float* b1 = (const float*)d_in[2];
  const float* W2 = (const float*)d_in[3];
  const float* b2 = (const float*)d_in[4];
  const float* W3 = (const float*)d_in[5];
  const float* b3 = (const float*)d_in[6];
  const int* esrc = (const int*)d_in[7];
  const int* edst = (const int*)d_in[8];

  char* w = (char*)d_ws;
  int*   cursor  = (int*)w;    w += align_up((size_t)NB_BKT * 4);
  int*   deg     = (int*)w;    w += align_up((size_t)N_NODES * 4);
  int*   offs    = (int*)w;    w += align_up((size_t)N_NODES * 4);
  float* inv_deg = (float*)w;  w += align_up((size_t)N_NODES * 4);
  int*   eidx    = (int*)w;    w += align_up((size_t)NB_BKT * BKT_CAP * 4);  // 7.6 MB padded CSR
  u16*   Wp1     = (u16*)w;    w += align_up((size_t)16384 * 2);
  u16*   Wp2     = (u16*)w;    w += align_up((size_t)16384 * 2);
  u16*   Wp3     = (u16*)w;    w += align_up((size_t)16384 * 2);
  u16*   T       = (u16*)w;    w += align_up((size_t)N_NODES * FEAT * 2);    // 25.6 MB

  // bucket buffer (15.2 MB) aliases T — T is dead during CSR build
  uint2* bbuf = (uint2*)T;

  // d_out (51.2 MB) hosts: H bf16 [0,25.6) | H8 fp8 [25.6,38.4) | X8 fp8 [38.4,51.2)
  u16* H  = (u16*)d_out;
  u32* H8 = (u32*)((char*)d_out + (size_t)N_NODES * FEAT * 2);
  u32* X8 = (u32*)((char*)d_out + (size_t)N_NODES * FEAT * 3);

  hipMemsetAsync(cursor, 0, (size_t)NB_BKT * 4, stream);

  bucket_scatter_kernel<<<NB_A, 256, 0, stream>>>(esrc, edst, cursor, bbuf);
  csr_build_kernel<<<NB_BKT, BKT_SIZE, 0, stream>>>(bbuf, cursor, offs, deg, inv_deg, eidx);

  wprep3_kernel<<<192, 256, 0, stream>>>(W1, W2, W3, Wp1, Wp2, Wp3);
  cvt_x8_kernel<<<N_EDGES / 256, 256, 0, stream>>>(x, (uint2*)X8);   // 1.6M threads

  const int AGG_BLOCKS  = (N_NODES + 3) / 4;
  const int GEMM_BLOCKS = (N_NODES + 127) / 128;
  const int CVT_BLOCKS  = N_EDGES / 256;   // 12.8M fp8 / 8 per thread / 256

  // layer 1: neighbors X8, self fp32 x -> T -> H
  agg8_kernel<1><<<AGG_BLOCKS, 256, 0, stream>>>(X8, (const u16*)nullptr, x,
                                                 offs, deg, inv_deg, eidx, T);
  gemm2_kernel<0><<<GEMM_BLOCKS, 256, 0, stream>>>(T, Wp1, b1, H);

  // layer 2
  cvt_h8_kernel<<<CVT_BLOCKS, 256, 0, stream>>>(H, (uint2*)H8);
  agg8_kernel<0><<<AGG_BLOCKS, 256, 0, stream>>>(H8, H, (const float*)nullptr,
                                                 offs, deg, inv_deg, eidx, T);
  gemm2_kernel<0><<<GEMM_BLOCKS, 256, 0, stream>>>(T, Wp2, b2, H);

  // layer 3
  cvt_h8_kernel<<<CVT_BLOCKS, 256, 0, stream>>>(H, (uint2*)H8);
  agg8_kernel<0><<<AGG_BLOCKS, 256, 0, stream>>>(H8, H, (const float*)nullptr,
                                                 offs, deg, inv_deg, eidx, T);
  gemm2_kernel<1><<<GEMM_BLOCKS, 256, 0, stream>>>(T, Wp3, b3, d_out);

  (void)in_sizes; (void)n_in; (void)out_size; (void)ws_size; (void)w;
}

// Round 5
// 340.170 us; speedup vs baseline: 2.0640x; 1.2557x over previous
//
#include <hip/hip_runtime.h>
#include <hip/hip_bf16.h>
#include <stdint.h>

#if __has_builtin(__builtin_amdgcn_cvt_pk_f32_fp8) && __has_builtin(__builtin_amdgcn_cvt_pk_fp8_f32)
#define FP8_HW 1
#else
#define FP8_HW 0
#include <hip/hip_fp8.h>
#endif

#define N_NODES 100000
#define N_EDGES 1600000
#define FEAT 128

#define BKT_SHIFT 8
#define BKT_SIZE  256
#define NB_BKT    391          // ceil(N_NODES / 256)
#define BKT_CAP   4864         // mean 4096 + ceil4 pad ~384 + 6-sigma headroom
#define NB_A      400          // blocks in edge passes
#define EPB       4000         // edges per block

typedef uint16_t u16;
typedef uint32_t u32;
typedef __attribute__((ext_vector_type(8))) short bf16x8;
typedef __attribute__((ext_vector_type(4))) float f32x4;
typedef __attribute__((ext_vector_type(2))) float f32x2;

__device__ __forceinline__ u16 bf16_rn(float f){
  u32 u = __float_as_uint(f);
  u += 0x7FFFu + ((u >> 16) & 1u);
  return (u16)(u >> 16);
}
__device__ __forceinline__ float bf16_lo(u32 p){ return __uint_as_float(p << 16); }
__device__ __forceinline__ float bf16_hi(u32 p){ return __uint_as_float(p & 0xFFFF0000u); }

__device__ __forceinline__ void fp8x4_to_f32(u32 w, float* o){
#if FP8_HW
  f32x2 a = __builtin_amdgcn_cvt_pk_f32_fp8(w, false);
  f32x2 b = __builtin_amdgcn_cvt_pk_f32_fp8(w, true);
  o[0] = a.x; o[1] = a.y; o[2] = b.x; o[3] = b.y;
#else
  #pragma unroll
  for (int i = 0; i < 4; ++i){
    __hip_fp8_e4m3 t; t.__x = (uint8_t)((w >> (8 * i)) & 0xFF);
    o[i] = (float)t;
  }
#endif
}
__device__ __forceinline__ u32 f32x4_to_fp8(float a, float b, float c, float d){
#if FP8_HW
  u32 r = __builtin_amdgcn_cvt_pk_fp8_f32(a, b, 0, false);
  r = __builtin_amdgcn_cvt_pk_fp8_f32(c, d, r, true);
  return r;
#else
  __hip_fp8_e4m3 qa(a), qb(b), qc(c), qd(d);
  return (u32)qa.__x | ((u32)qb.__x << 8) | ((u32)qc.__x << 16) | ((u32)qd.__x << 24);
#endif
}

// ---------------- CSR build: fixed-capacity bucket scatter + per-bucket sort ----------------

__global__ void bucket_scatter_kernel(const int* __restrict__ src, const int* __restrict__ dst,
                                      int* __restrict__ cursor, uint2* __restrict__ bbuf){
  __shared__ int h[NB_BKT];
  __shared__ int res[NB_BKT];
  for (int i = threadIdx.x; i < NB_BKT; i += 256) h[i] = 0;
  __syncthreads();
  int base = blockIdx.x * EPB;
  int end  = min(base + EPB, N_EDGES);
  for (int e = base + threadIdx.x; e < end; e += 256)
    atomicAdd(&h[dst[e] >> BKT_SHIFT], 1);
  __syncthreads();
  for (int i = threadIdx.x; i < NB_BKT; i += 256){
    int c = h[i];
    res[i] = c ? atomicAdd(&cursor[i], c) : 0;
    h[i] = 0;                       // reuse as local cursor
  }
  __syncthreads();
  for (int e = base + threadIdx.x; e < end; e += 256){
    int d = dst[e];
    int b = d >> BKT_SHIFT;
    int p = atomicAdd(&h[b], 1);
    bbuf[(size_t)b * BKT_CAP + res[b] + p] = make_uint2((u32)src[e], (u32)(d & (BKT_SIZE - 1)));
  }
}

// per-node segments padded to multiples of 4 entries (so agg can read uint4-aligned indices)
__global__ void csr_build_kernel(const uint2* __restrict__ bbuf, const int* __restrict__ cursor,
                                 int* __restrict__ offs, int* __restrict__ deg,
                                 float* __restrict__ inv_deg, int* __restrict__ eidx){
  __shared__ int hist[BKT_SIZE];
  __shared__ int s[BKT_SIZE];
  __shared__ int cu[BKT_SIZE];
  int b = blockIdx.x;
  int t = threadIdx.x;
  int lo = b * BKT_CAP;
  int hi = lo + cursor[b];
  hist[t] = 0;
  __syncthreads();
  for (int e = lo + t; e < hi; e += BKT_SIZE)
    atomicAdd(&hist[bbuf[e].y], 1);
  __syncthreads();
  int v  = hist[t];
  int pv = (v + 3) & ~3;            // padded length
  s[t] = pv;
  __syncthreads();
  for (int d = 1; d < BKT_SIZE; d <<= 1){
    int u = (t >= d) ? s[t - d] : 0;
    __syncthreads();
    s[t] += u;
    __syncthreads();
  }
  int excl = s[t] - pv;
  int node = b * BKT_SIZE + t;
  if (node < N_NODES){
    offs[node]    = lo + excl;
    deg[node]     = v;
    inv_deg[node] = 1.0f / fmaxf((float)v, 1.0f);
  }
  __syncthreads();
  s[t]  = excl;
  cu[t] = 0;
  __syncthreads();
  for (int e = lo + t; e < hi; e += BKT_SIZE){
    uint2 q = bbuf[e];
    int p = atomicAdd(&cu[q.y], 1);
    eidx[lo + s[q.y] + p] = (int)q.x;
  }
}

// ---------------- conversions ----------------

__global__ void cvt_x8_kernel(const float* __restrict__ x, uint2* __restrict__ X8){
  int i = blockIdx.x * 256 + threadIdx.x;        // < 1.6M
  const float4* p = (const float4*)x + (size_t)i * 2;
  float4 a = p[0], b = p[1];
  uint2 o;
  o.x = f32x4_to_fp8(a.x, a.y, a.z, a.w);
  o.y = f32x4_to_fp8(b.x, b.y, b.z, b.w);
  X8[i] = o;
}

__global__ void cvt_h8_kernel(const u16* __restrict__ H, uint2* __restrict__ H8){
  int i = blockIdx.x * 256 + threadIdx.x;        // < 1.6M
  uint4 hq = ((const uint4*)H)[i];
  uint2 o;
  o.x = f32x4_to_fp8(bf16_lo(hq.x), bf16_hi(hq.x), bf16_lo(hq.y), bf16_hi(hq.y));
  o.y = f32x4_to_fp8(bf16_lo(hq.z), bf16_hi(hq.z), bf16_lo(hq.w), bf16_hi(hq.w));
  H8[i] = o;
}

__global__ void wprep3_kernel(const float* __restrict__ W1, const float* __restrict__ W2,
                              const float* __restrict__ W3, u16* __restrict__ Wp1,
                              u16* __restrict__ Wp2, u16* __restrict__ Wp3){
  int which = blockIdx.x >> 6;
  int b     = blockIdx.x & 63;
  const float* W = (which == 0) ? W1 : (which == 1) ? W2 : W3;
  u16*        Wp = (which == 0) ? Wp1 : (which == 1) ? Wp2 : Wp3;
  int idx = b * 256 + threadIdx.x;              // 0..16383
  int j    = idx & 7;
  int lane = (idx >> 3) & 63;
  int t    = idx >> 9;
  int k0 = t & 3, n0 = t >> 2;
  int k = k0 * 32 + (lane >> 4) * 8 + j;
  int n = n0 * 16 + (lane & 15);
  Wp[idx] = bf16_rn(W[k * FEAT + n]);
}

// ---------------- aggregation: 4 nodes/wave, fp8 neighbors, no cross-lane reduce ----------------
// lane = nsub*16 + slice; nsub in 0..3 = node sub-index, slice in 0..15 = 8-feat chunk (8 B fp8).
// Per iteration: one uint4 broadcast gives 4 edge indices; 4 row loads (uint2) accumulate into
// the same 8 lane accumulators. Tail masked by fmac weight; indices clamped to row 0.
template<int SM>
__global__ void agg16_kernel(const u32* __restrict__ n8,     // fp8 table, row = 32 u32
                             const u16* __restrict__ hb,     // bf16 self table (SM=0)
                             const float* __restrict__ xf,   // fp32 self table (SM=1)
                             const int* __restrict__ offs,
                             const int* __restrict__ deg,
                             const float* __restrict__ inv_deg,
                             const int* __restrict__ eidx,
                             u16* __restrict__ T){
  int wid   = (int)((blockIdx.x * 256u + threadIdx.x) >> 6);
  int lane  = threadIdx.x & 63;
  int nsub  = lane >> 4;
  int slice = lane & 15;
  int node  = wid * 4 + nsub;
  bool vn   = node < N_NODES;
  int nc    = vn ? node : 0;
  int start = offs[nc];
  int cnt   = vn ? deg[nc] : 0;
  const int* ep = eidx + start;            // 16-B aligned (padded CSR)

  float acc[8];
  #pragma unroll
  for (int j = 0; j < 8; ++j) acc[j] = 0.f;

  uint4 q = (cnt > 0) ? *(const uint4*)ep : make_uint4(0, 0, 0, 0);

  for (int e = 0; e < cnt; e += 4){
    uint4 qn = *(const uint4*)(ep + e + 4);   // prefetch (stays within bucket capacity)
    int i0 = (int)q.x, i1 = (int)q.y, i2 = (int)q.z, i3 = (int)q.w;
    float f0 = 1.f;                            // e+0 < cnt always (loop condition)
    float f1 = (e + 1 < cnt) ? 1.f : 0.f; if (e + 1 >= cnt) i1 = 0;
    float f2 = (e + 2 < cnt) ? 1.f : 0.f; if (e + 2 >= cnt) i2 = 0;
    float f3 = (e + 3 < cnt) ? 1.f : 0.f; if (e + 3 >= cnt) i3 = 0;
    uint2 r0 = *(const uint2*)(n8 + (size_t)i0 * 32 + slice * 2);
    uint2 r1 = *(const uint2*)(n8 + (size_t)i1 * 32 + slice * 2);
    uint2 r2 = *(const uint2*)(n8 + (size_t)i2 * 32 + slice * 2);
    uint2 r3 = *(const uint2*)(n8 + (size_t)i3 * 32 + slice * 2);
    float t0[4], t1[4];
    fp8x4_to_f32(r0.x, t0); fp8x4_to_f32(r0.y, t1);
    acc[0]+=f0*t0[0]; acc[1]+=f0*t0[1]; acc[2]+=f0*t0[2]; acc[3]+=f0*t0[3];
    acc[4]+=f0*t1[0]; acc[5]+=f0*t1[1]; acc[6]+=f0*t1[2]; acc[7]+=f0*t1[3];
    fp8x4_to_f32(r1.x, t0); fp8x4_to_f32(r1.y, t1);
    acc[0]+=f1*t0[0]; acc[1]+=f1*t0[1]; acc[2]+=f1*t0[2]; acc[3]+=f1*t0[3];
    acc[4]+=f1*t1[0]; acc[5]+=f1*t1[1]; acc[6]+=f1*t1[2]; acc[7]+=f1*t1[3];
    fp8x4_to_f32(r2.x, t0); fp8x4_to_f32(r2.y, t1);
    acc[0]+=f2*t0[0]; acc[1]+=f2*t0[1]; acc[2]+=f2*t0[2]; acc[3]+=f2*t0[3];
    acc[4]+=f2*t1[0]; acc[5]+=f2*t1[1]; acc[6]+=f2*t1[2]; acc[7]+=f2*t1[3];
    fp8x4_to_f32(r3.x, t0); fp8x4_to_f32(r3.y, t1);
    acc[0]+=f3*t0[0]; acc[1]+=f3*t0[1]; acc[2]+=f3*t0[2]; acc[3]+=f3*t0[3];
    acc[4]+=f3*t1[0]; acc[5]+=f3*t1[1]; acc[6]+=f3*t1[2]; acc[7]+=f3*t1[3];
    q = qn;
  }

  if (!vn) return;
  float w = inv_deg[node];
  float self[8];
  if (SM == 1){
    const float* sp = xf + (size_t)node * FEAT + slice * 8;
    float4 a = *(const float4*)sp;
    float4 b = *(const float4*)(sp + 4);
    self[0]=a.x; self[1]=a.y; self[2]=a.z; self[3]=a.w;
    self[4]=b.x; self[5]=b.y; self[6]=b.z; self[7]=b.w;
  } else {
    const u16* sp = hb + (size_t)node * FEAT + slice * 8;
    uint4 s0 = *(const uint4*)sp;
    self[0]=bf16_lo(s0.x); self[1]=bf16_hi(s0.x); self[2]=bf16_lo(s0.y); self[3]=bf16_hi(s0.y);
    self[4]=bf16_lo(s0.z); self[5]=bf16_hi(s0.z); self[6]=bf16_lo(s0.w); self[7]=bf16_hi(s0.w);
  }
  uint4 o;
  o.x = (u32)bf16_rn(self[0] + w*acc[0]) | ((u32)bf16_rn(self[1] + w*acc[1]) << 16);
  o.y = (u32)bf16_rn(self[2] + w*acc[2]) | ((u32)bf16_rn(self[3] + w*acc[3]) << 16);
  o.z = (u32)bf16_rn(self[4] + w*acc[4]) | ((u32)bf16_rn(self[5] + w*acc[5]) << 16);
  o.w = (u32)bf16_rn(self[6] + w*acc[6]) | ((u32)bf16_rn(self[7] + w*acc[7]) << 16);
  *(uint4*)(T + (size_t)node * FEAT + slice * 8) = o;
}

// ---------------- GEMM: 32 rows/wave (2 tiles share B fragments), 128 rows/block ----------------
template<int MODE>   // 0: bf16 + relu; 1: fp32, no relu
__global__ __launch_bounds__(256) void gemm2_kernel(const u16* __restrict__ T,
                                                    const u16* __restrict__ Wp,
                                                    const float* __restrict__ bias,
                                                    void* __restrict__ out){
  int wave = threadIdx.x >> 6;
  int lane = threadIdx.x & 63;
  int row0 = blockIdx.x * 128 + wave * 32;
  if (row0 >= N_NODES) return;
  int quad = lane >> 4;
  int c    = lane & 15;

  f32x4 acc[2][8];
  #pragma unroll
  for (int t = 0; t < 2; ++t)
    #pragma unroll
    for (int i = 0; i < 8; ++i) acc[t][i] = (f32x4){0.f, 0.f, 0.f, 0.f};

  bf16x8 A[2][4];
  const u16* ar0 = T + (size_t)(row0 + c) * FEAT + quad * 8;
  const u16* ar1 = ar0 + 16 * FEAT;
  #pragma unroll
  for (int k0 = 0; k0 < 4; ++k0){
    A[0][k0] = *(const bf16x8*)(ar0 + k0 * 32);
    A[1][k0] = *(const bf16x8*)(ar1 + k0 * 32);
  }

  #pragma unroll
  for (int n0 = 0; n0 < 8; ++n0){
    #pragma unroll
    for (int k0 = 0; k0 < 4; ++k0){
      bf16x8 b = *(const bf16x8*)(Wp + (((n0 << 2) | k0) * 64 + lane) * 8);
      acc[0][n0] = __builtin_amdgcn_mfma_f32_16x16x32_bf16(A[0][k0], b, acc[0][n0], 0, 0, 0);
      acc[1][n0] = __builtin_amdgcn_mfma_f32_16x16x32_bf16(A[1][k0], b, acc[1][n0], 0, 0, 0);
    }
  }

  #pragma unroll
  for (int t = 0; t < 2; ++t){
    #pragma unroll
    for (int n0 = 0; n0 < 8; ++n0){
      float bv = bias[n0 * 16 + c];
      #pragma unroll
      for (int r = 0; r < 4; ++r){
        int row = row0 + t * 16 + quad * 4 + r;
        int col = n0 * 16 + c;
        float v = acc[t][n0][r] + bv;
        if (MODE == 0){
          v = fmaxf(v, 0.f);
          ((u16*)out)[(size_t)row * FEAT + col] = bf16_rn(v);
        } else {
          ((float*)out)[(size_t)row * FEAT + col] = v;
        }
      }
    }
  }
}

// ---------------- launch ----------------

static inline size_t align_up(size_t x){ return (x + 255) & ~(size_t)255; }

extern "C" void kernel_launch(void* const* d_in, const int* in_sizes, int n_in,
                              void* d_out, int out_size, void* d_ws, size_t ws_size,
                              hipStream_t stream){
  const float* x  = (const float*)d_in[0];
  const float* W1 = (const float*)d_in[1];
  const float* b1 = (const float*)d_in[2];
  const float* W2 = (const float*)d_in[3];
  const float* b2 = (const float*)d_in[4];
  const float* W3 = (const float*)d_in[5];
  const float* b3 = (const float*)d_in[6];
  const int* esrc = (const int*)d_in[7];
  const int* edst = (const int*)d_in[8];

  char* w = (char*)d_ws;
  int*   cursor  = (int*)w;    w += align_up((size_t)NB_BKT * 4);
  int*   deg     = (int*)w;    w += align_up((size_t)N_NODES * 4);
  int*   offs    = (int*)w;    w += align_up((size_t)N_NODES * 4);
  float* inv_deg = (float*)w;  w += align_up((size_t)N_NODES * 4);
  int*   eidx    = (int*)w;    w += align_up((size_t)NB_BKT * BKT_CAP * 4);  // padded CSR
  u16*   Wp1     = (u16*)w;    w += align_up((size_t)16384 * 2);
  u16*   Wp2     = (u16*)w;    w += align_up((size_t)16384 * 2);
  u16*   Wp3     = (u16*)w;    w += align_up((size_t)16384 * 2);
  u16*   T       = (u16*)w;    w += align_up((size_t)N_NODES * FEAT * 2);    // 25.6 MB

  // bucket buffer (15.2 MB) aliases T — T is dead during CSR build
  uint2* bbuf = (uint2*)T;

  // d_out (51.2 MB) hosts: H bf16 [0,25.6) | H8 fp8 [25.6,38.4) | X8 fp8 [38.4,51.2)
  u16* H  = (u16*)d_out;
  u32* H8 = (u32*)((char*)d_out + (size_t)N_NODES * FEAT * 2);
  u32* X8 = (u32*)((char*)d_out + (size_t)N_NODES * FEAT * 3);

  hipMemsetAsync(cursor, 0, (size_t)NB_BKT * 4, stream);

  bucket_scatter_kernel<<<NB_A, 256, 0, stream>>>(esrc, edst, cursor, bbuf);
  csr_build_kernel<<<NB_BKT, BKT_SIZE, 0, stream>>>(bbuf, cursor, offs, deg, inv_deg, eidx);

  wprep3_kernel<<<192, 256, 0, stream>>>(W1, W2, W3, Wp1, Wp2, Wp3);
  cvt_x8_kernel<<<N_EDGES / 256, 256, 0, stream>>>(x, (uint2*)X8);

  const int AGG_BLOCKS  = (N_NODES + 15) / 16;        // 4 nodes/wave, 4 waves/block
  const int GEMM_BLOCKS = (N_NODES + 127) / 128;
  const int CVT_BLOCKS  = N_EDGES / 256;

  // layer 1: neighbors X8, self fp32 x -> T -> H
  agg16_kernel<1><<<AGG_BLOCKS, 256, 0, stream>>>(X8, (const u16*)nullptr, x,
                                                  offs, deg, inv_deg, eidx, T);
  gemm2_kernel<0><<<GEMM_BLOCKS, 256, 0, stream>>>(T, Wp1, b1, H);

  // layer 2
  cvt_h8_kernel<<<CVT_BLOCKS, 256, 0, stream>>>(H, (uint2*)H8);
  agg16_kernel<0><<<AGG_BLOCKS, 256, 0, stream>>>(H8, H, (const float*)nullptr,
                                                  offs, deg, inv_deg, eidx, T);
  gemm2_kernel<0><<<GEMM_BLOCKS, 256, 0, stream>>>(T, Wp2, b2, H);

  // layer 3
  cvt_h8_kernel<<<CVT_BLOCKS, 256, 0, stream>>>(H, (uint2*)H8);
  agg16_kernel<0><<<AGG_BLOCKS, 256, 0, stream>>>(H8, H, (const float*)nullptr,
                                                  offs, deg, inv_deg, eidx, T);
  gemm2_kernel<1><<<GEMM_BLOCKS, 256, 0, stream>>>(T, Wp3, b3, d_out);

  (void)in_sizes; (void)n_in; (void)out_size; (void)ws_size; (void)w;
}